// Round 5
// baseline (141.749 us; speedup 1.0000x reference)
//
#include <hip/hip_runtime.h>

#define NPTS  65536
#define KNB   32
#define KPn   15
#define CIN   64
#define COUT  128
#define MPTS  16            // points per tile (MFMA M of GEMM2)
#define THREADS 512         // 8 waves/block; 4 blocks/CU = 32 waves/CU
#define NT    4             // tiles per block (software-pipelined)
#define RCAP  96            // radius-candidate cap
#define CHUNK 32            // survivors per GEMM1 K-chunk
#define ESTR  40            // infl/sfT row stride (elems): 80 B, 16B-aligned
#define WSTR  1032          // wl row stride (elems): 1024 + 8 pad = 2064 B
#define KSTEPS 32           // GEMM2 K steps (1024/32); k=15 rows are zero pad
#define NTILE 8             // 128 cols / 16
#define WELEMS (NTILE * KSTEPS * 64 * 8)    // 131072 bf16 elements

// pool map (bytes):
//   [0 .. 16512)      wl rows 0-7  (written at end of pass 0)
//   [16512 .. 33024)  wl rows 8-15 (written at end of pass 1)
//   scratch infl[128][ESTR] (10240 B) + sfT[64][ESTR] (5120 B) at 16512:
//   overlays wl rows 8-15, which are written only after the last scratch
//   read (barrier-ordered), and re-zeroed only after GEMM2 reads (barrier).
#define POOL_BYTES (MPTS * WSTR * 2)        // 33024
#define OFF_SCR    16512
#define OFF_SFT    (OFF_SCR + 128 * ESTR * 2)   // 26752
#define ZINFL_B16  (128 * ESTR * 2 / 16)        // 640 uint4 zeroed per chunk

typedef __attribute__((ext_vector_type(8))) short short8;
typedef __attribute__((ext_vector_type(4))) float f32x4;

__device__ __forceinline__ unsigned int f2bf(float f) {
    union { float f; unsigned int i; } v; v.f = f;
    return (v.i + 0x7fffu + ((v.i >> 16) & 1u)) >> 16;   // RNE
}
__device__ __forceinline__ unsigned int cvt_pk_bf16(float lo, float hi) {
    unsigned int r;
    asm volatile("v_cvt_pk_bf16_f32 %0, %1, %2" : "=v"(r) : "v"(lo), "v"(hi));
    return r;
}

// ---- prep: pack weights into MFMA B-fragment order + kpq/R2 ----
// GEMM2 K-enum: f in [0,1024), k = f&15 (k==15 -> zero pad), c = f>>4.
__global__ void wtrans_kernel(const float* __restrict__ w,
                              const float* __restrict__ kpts,
                              unsigned short* __restrict__ wTf,
                              float4* __restrict__ kpq_out) {  // [16]: 15 kpq + {R2}
    const int d = blockIdx.x * 256 + threadIdx.x;
    if (d < WELEMS) {
        const int j    = d & 7;
        const int lane = (d >> 3) & 63;
        const int ks   = (d >> 9) & 31;
        const int t    = d >> 14;
        const int f    = ks * 32 + ((lane >> 4) & 3) * 8 + j;
        const int k    = f & 15;
        const int c    = f >> 4;
        const int n    = t * 16 + (lane & 15);
        wTf[d] = (k < KPn)
            ? (unsigned short)f2bf(w[((size_t)k * CIN + c) * COUT + n])
            : (unsigned short)0;
    }
    if (blockIdx.x == 0 && threadIdx.x < 16) {
        const int k = threadIdx.x;
        if (k < KPn) {
            const float x = kpts[k * 3 + 0];
            const float y = kpts[k * 3 + 1];
            const float z = kpts[k * 3 + 2];
            kpq_out[k] = make_float4(x, y, z, x * x + y * y + z * z);
        } else {
            float mx = 0.f;
            for (int i = 0; i < KPn; ++i) {
                const float x = kpts[i * 3 + 0];
                const float y = kpts[i * 3 + 1];
                const float z = kpts[i * 3 + 2];
                mx = fmaxf(mx, x * x + y * y + z * z);
            }
            const float R = 0.1f + sqrtf(mx);
            kpq_out[15] = make_float4(R * R, 0.f, 0.f, 0.f);
        }
    }
}

__global__ __launch_bounds__(THREADS, 8) void kpconv_kernel(
    const float* __restrict__ pos,         // [N,3] f32
    const float* __restrict__ feats,       // [N,64] f32
    const unsigned short* __restrict__ wTf,// fragment-packed bf16 weights
    const float4* __restrict__ kpq_in,     // [16] precomputed kpq + R2
    const int*   __restrict__ neighbors,   // [N,32] int32
    float*       __restrict__ out)         // [N,128] f32
{
    __shared__ __align__(16) unsigned char pool[POOL_BYTES];
    __shared__ float  cposf[2][MPTS * 3];
    __shared__ float4 kpq[KPn];
    __shared__ float  rlx[2][RCAP], rly[2][RCAP], rlz[2][RCAP], rld[2][RCAP];
    __shared__ unsigned int rsl[2][RCAP];  // (p<<16) | nb
    __shared__ int    nact[2];

    unsigned short* const wl   = (unsigned short*)pool;
    unsigned short* const infl = (unsigned short*)(pool + OFF_SCR); // [128][ESTR]
    unsigned short* const sfT  = (unsigned short*)(pool + OFF_SFT); // [64][ESTR]

    const int tid  = threadIdx.x;
    const int lane = tid & 63;
    const int wv   = tid >> 6;             // wave id 0..7 = p_local (per pass)
    const int m    = lane & 15;
    const int q    = lane >> 4;
    const int p0   = tid >> 5;
    const int tile0 = blockIdx.x * NT;

    // ---- prologue: prefetch tile 0's gather chain ----
    int   nbp, n0p = tile0 * MPTS;
    float qxp, qyp, qzp;
    nbp = neighbors[(size_t)n0p * KNB + tid];
    qxp = pos[(size_t)nbp * 3 + 0];
    qyp = pos[(size_t)nbp * 3 + 1];
    qzp = pos[(size_t)nbp * 3 + 2];
    const float R2 = kpq_in[15].x;         // uniform

    if (tid < KPn) kpq[tid] = kpq_in[tid];
    if (tid < 2)  nact[tid] = 0;
    if (tid < MPTS * 3) cposf[0][tid] = pos[(size_t)n0p * 3 + tid];
    __syncthreads();

    // ---- compact tile 0 into buffer 0 ----
    {
        const float rx = qxp - cposf[0][p0 * 3 + 0];
        const float ry = qyp - cposf[0][p0 * 3 + 1];
        const float rz = qzp - cposf[0][p0 * 3 + 2];
        const float d2r = rx * rx + ry * ry + rz * rz;
        if (d2r < R2) {                            // ~6% survive
            const int idx = atomicAdd(&nact[0], 1);
            if (idx < RCAP) {
                rlx[0][idx] = rx; rly[0][idx] = ry; rlz[0][idx] = rz;
                rld[0][idx] = d2r;
                rsl[0][idx] = ((unsigned int)p0 << 16) | (unsigned int)nbp;
            }
        }
    }
    __syncthreads();

    for (int t = 0; t < NT; ++t) {
        const int  cur = t & 1, nxt = cur ^ 1;
        const int  n0  = (tile0 + t) * MPTS;
        const bool hasnext = (t + 1 < NT);
        const int  E   = min(nact[cur], RCAP);
        const int  nch = max(1, (E + CHUNK - 1) >> 5);

        // issue t+1's independent loads now (regs; consumed 2+ barriers later)
        float cpf = 0.f;
        if (hasnext) {
            nbp = neighbors[(size_t)(n0 + MPTS) * KNB + tid];
            if (tid < MPTS * 3) cpf = pos[(size_t)(n0 + MPTS) * 3 + tid];
        }

        for (int pass = 0; pass < 2; ++pass) {
            // pass-1 top: nbp has returned; issue dependent pos gather now
            if (pass == 1 && hasnext) {
                qxp = pos[(size_t)nbp * 3 + 0];
                qyp = pos[(size_t)nbp * 3 + 1];
                qzp = pos[(size_t)nbp * 3 + 2];
                if (tid < MPTS * 3) cposf[nxt][tid] = cpf;
            }

            f32x4 acc[4];
            #pragma unroll
            for (int nt = 0; nt < 4; ++nt) acc[nt] = (f32x4){0.f, 0.f, 0.f, 0.f};

            const bool skip_stage = (pass == 1 && nch == 1);  // sfT persists

            for (int ch = 0; ch < nch; ++ch) {
                const int ce = min(E - ch * CHUNK, CHUNK);

                // ---- phase A: zero infl; stage sfT; pipeline bookkeeping ----
                {
                    uint4* zp = (uint4*)infl;
                    #pragma unroll
                    for (int i = 0; i < 2; ++i) {
                        const int idx = tid + i * THREADS;
                        if (idx < ZINFL_B16) zp[idx] = make_uint4(0u, 0u, 0u, 0u);
                    }
                    if (!skip_stage) {
                        const int el = tid & 31;
                        const int c4 = tid >> 5;          // 0..15
                        float4 f = make_float4(0.f, 0.f, 0.f, 0.f);
                        if (el < ce) {
                            const int nb = (int)(rsl[cur][ch * CHUNK + el] & 0xFFFFu);
                            f = *(const float4*)(feats + (size_t)nb * CIN + c4 * 4);
                        }
                        sfT[(c4 * 4 + 0) * ESTR + el] = (unsigned short)f2bf(f.x);
                        sfT[(c4 * 4 + 1) * ESTR + el] = (unsigned short)f2bf(f.y);
                        sfT[(c4 * 4 + 2) * ESTR + el] = (unsigned short)f2bf(f.z);
                        sfT[(c4 * 4 + 3) * ESTR + el] = (unsigned short)f2bf(f.w);
                    }
                    if (pass == 0 && ch == 0 && tid == 0) nact[nxt] = 0;
                }
                __syncthreads();

                // ---- phase B: kp test -> direct scatter (this p-half) ----
                if (tid < ce * 16) {
                    const int el = tid >> 4;
                    const int k  = tid & 15;
                    if (k < KPn) {
                        const int e = ch * CHUNK + el;
                        const int p = (int)(rsl[cur][e] >> 16);
                        if ((p >> 3) == pass) {
                            const float4 kp  = kpq[k];
                            const float  d2r = rld[cur][e];
                            const float dot = rlx[cur][e] * kp.x +
                                              rly[cur][e] * kp.y +
                                              rlz[cur][e] * kp.z;
                            if (dot > 0.5f * (d2r - 0.01f + kp.w)) {
                                const float d2 = fmaxf(d2r - 2.f * dot + kp.w, 0.f);
                                const float w  = 1.0f - 10.0f * sqrtf(d2);
                                infl[((p & 7) * 16 + k) * ESTR + el] =
                                    (unsigned short)f2bf(w);
                            }
                        }
                    }
                }
                __syncthreads();

                // ---- phase C: MFMA; overlap t+1's radius/compact here ----
                {
                    const short8 a = *(const short8*)(infl + (wv * 16 + m) * ESTR + q * 8);
                    #pragma unroll
                    for (int nt = 0; nt < 4; ++nt) {
                        const short8 b = *(const short8*)(sfT + (nt * 16 + m) * ESTR + q * 8);
                        acc[nt] = __builtin_amdgcn_mfma_f32_16x16x32_bf16(a, b, acc[nt], 0, 0, 0);
                    }
                }
                if (pass == 1 && ch == nch - 1 && hasnext) {
                    const float rx = qxp - cposf[nxt][p0 * 3 + 0];
                    const float ry = qyp - cposf[nxt][p0 * 3 + 1];
                    const float rz = qzp - cposf[nxt][p0 * 3 + 2];
                    const float d2r = rx * rx + ry * ry + rz * rz;
                    if (d2r < R2) {
                        const int idx = atomicAdd(&nact[nxt], 1);
                        if (idx < RCAP) {
                            rlx[nxt][idx] = rx; rly[nxt][idx] = ry;
                            rlz[nxt][idx] = rz; rld[nxt][idx] = d2r;
                            rsl[nxt][idx] = ((unsigned int)p0 << 16) |
                                            (unsigned int)nbp;
                        }
                    }
                }
                __syncthreads();   // scratch reads + compact done
            }

            // epilogue: weighted f32 -> bf16 -> wl row (pass*8 + wv)
            // D layout: col c = m (within n-tile), rows k = q*4 + r
            {
                const int prow = pass * 8 + wv;
                #pragma unroll
                for (int nt = 0; nt < 4; ++nt) {
                    const int c = nt * 16 + m;
                    unsigned short* wp = wl + prow * WSTR + c * 16 + q * 4;
                    *(unsigned int*)(wp)     = cvt_pk_bf16(acc[nt][0], acc[nt][1]);
                    *(unsigned int*)(wp + 2) = cvt_pk_bf16(acc[nt][2], acc[nt][3]);
                }
            }
        }
        __syncthreads();   // wl fully written

        // ---- GEMM2: out[16][128] = wl[16][1024] @ W; dual acc chains ----
        {
            f32x4 o0 = {0.f, 0.f, 0.f, 0.f};
            f32x4 o1 = {0.f, 0.f, 0.f, 0.f};
            const unsigned short* ap = wl + m * WSTR + q * 8;
            const short8* bp = (const short8*)wTf + (size_t)wv * KSTEPS * 64 + lane;

            #pragma unroll 2
            for (int ks = 0; ks < KSTEPS; ks += 2) {
                const short8 a0 = *(const short8*)(ap + ks * 32);
                const short8 b0 = bp[ks * 64];
                o0 = __builtin_amdgcn_mfma_f32_16x16x32_bf16(a0, b0, o0, 0, 0, 0);
                const short8 a1 = *(const short8*)(ap + (ks + 1) * 32);
                const short8 b1 = bp[(ks + 1) * 64];
                o1 = __builtin_amdgcn_mfma_f32_16x16x32_bf16(a1, b1, o1, 0, 0, 0);
            }
            o0 = o0 + o1;

            const int c = wv * 16 + m;
            #pragma unroll
            for (int r = 0; r < 4; ++r)
                out[(size_t)(n0 + q * 4 + r) * COUT + c] = o0[r];
        }
        __syncthreads();   // protect wl/scratch before next tile's phase A
    }
}

extern "C" void kernel_launch(void* const* d_in, const int* in_sizes, int n_in,
                              void* d_out, int out_size, void* d_ws, size_t ws_size,
                              hipStream_t stream) {
    const float* pos       = (const float*)d_in[0];
    const float* feats     = (const float*)d_in[1];
    const float* kpts      = (const float*)d_in[2];
    const float* weights   = (const float*)d_in[3];
    const int*   neighbors = (const int*)d_in[4];
    float*       out       = (float*)d_out;
    unsigned short* wTf    = (unsigned short*)d_ws;               // 262144 B
    float4* kpq            = (float4*)((char*)d_ws + WELEMS * 2); // 256 B

    wtrans_kernel<<<WELEMS / 256, 256, 0, stream>>>(weights, kpts, wTf, kpq);
    kpconv_kernel<<<NPTS / MPTS / NT, THREADS, 0, stream>>>(
        pos, feats, wTf, kpq, neighbors, out);
}